// Round 14
// baseline (132.373 us; speedup 1.0000x reference)
//
#include <hip/hip_runtime.h>
#include <math.h>

typedef __bf16 bf16;
typedef __bf16 bf16x4 __attribute__((ext_vector_type(4)));
typedef __bf16 bf16x8 __attribute__((ext_vector_type(8)));
typedef float f32x4 __attribute__((ext_vector_type(4)));

static constexpr int NB = 2, NS = 2048, ND = 1024, NH = 16, NDK = 64;
static constexpr float LOG2E = 1.442695041f;

__device__ __forceinline__ f32x4 mfma16(bf16x8 a, bf16x8 b, f32x4 c) {
  return __builtin_amdgcn_mfma_f32_16x16x32_bf16(a, b, c, 0, 0, 0);
}

__device__ __forceinline__ float exp2_fast(float x) {
  return __builtin_amdgcn_exp2f(x);
}

// async global->LDS, 16B per lane; dest = wave-uniform base + lane*16
__device__ __forceinline__ void gload16(const void* g, void* l) {
  __builtin_amdgcn_global_load_lds(
      (const __attribute__((address_space(1))) void*)g,
      (__attribute__((address_space(3))) void*)l, 16, 0, 0);
}

// ---------------- W fp32->bf16 convert (y=0..3) + prep (y==4) ----------------
__global__ __launch_bounds__(256) void cvtw_prep(
    const float* __restrict__ s0, const float* __restrict__ s1,
    const float* __restrict__ s2, const float* __restrict__ s3,
    bf16* __restrict__ d0, bf16* __restrict__ d1,
    bf16* __restrict__ d2, bf16* __restrict__ d3, int n8w,
    const float* __restrict__ pds, float* __restrict__ scale,
    const float* __restrict__ mask, int* __restrict__ flag, int n4) {
  const int y = blockIdx.y;
  if (y == 4) {
    if (blockIdx.x == 0 && threadIdx.x < NDK) {
      float x = pds[threadIdx.x];
      float sp = fmaxf(x, 0.0f) + log1pf(expf(-fabsf(x)));
      scale[threadIdx.x] = (LOG2E * LOG2E / 8.0f) * sp;
    }
    int idx = blockIdx.x * blockDim.x + threadIdx.x;
    int stride = 256 * blockDim.x;
    unsigned acc = 0;
    for (int i = idx; i < n4; i += stride) {
      float4 v = ((const float4*)mask)[i];
      acc |= (__float_as_uint(v.x) << 1) | (__float_as_uint(v.y) << 1)
           | (__float_as_uint(v.z) << 1) | (__float_as_uint(v.w) << 1);
    }
    if (acc != 0) atomicOr(flag, 1);
    return;
  }
  const float* s = y == 0 ? s0 : y == 1 ? s1 : y == 2 ? s2 : s3;
  bf16* d = y == 0 ? d0 : y == 1 ? d1 : y == 2 ? d2 : d3;
  for (int i = blockIdx.x * 256 + threadIdx.x; i < n8w; i += gridDim.x * 256) {
    const float4* f = (const float4*)s + 2 * (size_t)i;
    float4 a = f[0], b = f[1];
    bf16x8 o;
    o[0] = (bf16)a.x; o[1] = (bf16)a.y; o[2] = (bf16)a.z; o[3] = (bf16)a.w;
    o[4] = (bf16)b.x; o[5] = (bf16)b.y; o[6] = (bf16)b.z; o[7] = (bf16)b.w;
    *((bf16x8*)d + i) = o;
  }
}

// ---------------- fused QKV GEMM: fp32-X direct, XCD-swizzled block mapping --------------
// Panel-sharing index lives in blockIdx.x bits 0-4: the 8 blocks sharing one X panel all
// satisfy x % 8 == const -> same XCD -> X panel fetched once into that XCD's L2 (fixes
// R12's 8x cross-XCD refetch). which 0: Qs; 1: Ks; 2: Vt = Wv @ Xv^T -> [B,H,DK,S].
__global__ __launch_bounds__(256) void qkv_mm(
    const float* __restrict__ Xqf, const float* __restrict__ Xkf, const float* __restrict__ Xvf,
    const bf16* __restrict__ Wqb, const bf16* __restrict__ Wkb, const bf16* __restrict__ Wvb,
    const float* __restrict__ bq, const float* __restrict__ bk, const float* __restrict__ bv,
    const float* __restrict__ scale2,
    bf16* __restrict__ Qs, bf16* __restrict__ Ks, bf16* __restrict__ Vt, int mode0) {
  __shared__ __align__(16) bf16 la[128 * 64];
  __shared__ __align__(16) bf16 lb[128 * 64];
  const int which = mode0 + blockIdx.y;
  const int t = threadIdx.x, lane = t & 63, wave = t >> 6;
  const int wm = wave >> 1, wn = wave & 1;
  // XCD-aware mapping: X-panel index in low 5 bits (32 panels), other dim in high 3 bits
  int bm, bn;
  if (which == 2) { bn = blockIdx.x & 31; bm = blockIdx.x >> 5; }   // bn = token panel (X)
  else            { bm = blockIdx.x & 31; bn = blockIdx.x >> 5; }   // bm = token panel (X)
  const int g = lane >> 4, l15 = lane & 15;
  const int sr = wave * 8 + (lane >> 3);
  const int sc = ((lane & 7) ^ (lane >> 3)) * 8;   // pre-swizzled source col (elements)

  const float* Xf = which == 0 ? Xqf : which == 1 ? Xkf : Xvf;
  const float* Xbase = Xf + (size_t)((which == 2 ? bn : bm) * 128) * ND;
  const bf16* Wb = which == 0 ? Wqb : which == 1 ? Wkb : Wvb;
  const bf16* Wbase = Wb + (size_t)((which == 2 ? bm : bn) * 128) * ND;
  bf16* ldsX = (which == 2) ? lb : la;
  bf16* ldsW = (which == 2) ? la : lb;

  f32x4 acc[4][4] = {};

  for (int kt = 0; kt < ND; kt += 64) {
    for (int c = 0; c < 4; ++c)
      gload16(Wbase + (size_t)(c * 32 + sr) * ND + kt + sc, ldsW + c * 2048 + wave * 512);
    for (int c = 0; c < 4; ++c) {
      const float* gp = Xbase + (size_t)(c * 32 + sr) * ND + kt + sc;
      float4 a0 = *(const float4*)gp;
      float4 a1 = *(const float4*)(gp + 4);
      bf16x8 o;
      o[0] = (bf16)a0.x; o[1] = (bf16)a0.y; o[2] = (bf16)a0.z; o[3] = (bf16)a0.w;
      o[4] = (bf16)a1.x; o[5] = (bf16)a1.y; o[6] = (bf16)a1.z; o[7] = (bf16)a1.w;
      *(bf16x8*)(ldsX + c * 2048 + wave * 512 + lane * 8) = o;
    }
    __syncthreads();
    __builtin_amdgcn_s_setprio(1);
    for (int kk = 0; kk < 2; ++kk) {
      bf16x8 af[4], bfv[4];
      for (int m = 0; m < 4; ++m) {
        const int rr = wm * 64 + m * 16 + l15;
        af[m] = *(const bf16x8*)&la[rr * 64 + (((g + 4 * kk) ^ (rr & 7)) << 3)];
      }
      for (int n = 0; n < 4; ++n) {
        const int rr = wn * 64 + n * 16 + l15;
        bfv[n] = *(const bf16x8*)&lb[rr * 64 + (((g + 4 * kk) ^ (rr & 7)) << 3)];
      }
      for (int m = 0; m < 4; ++m)
        for (int n = 0; n < 4; ++n)
          acc[m][n] = mfma16(af[m], bfv[n], acc[m][n]);
    }
    __builtin_amdgcn_s_setprio(0);
    __syncthreads();
  }

  const int lr4 = g * 4;
  if (which != 2) {
    const float* bias = which ? bk : bq;
    bf16* outp = which ? Ks : Qs;
    for (int m = 0; m < 4; ++m) {
      const int grow0 = bm * 128 + wm * 64 + m * 16 + lr4;
      for (int n = 0; n < 4; ++n) {
        const int gcol = bn * 128 + wn * 64 + n * 16 + l15;
        const int h = gcol >> 6, dk = gcol & 63;
        const float bia = bias[gcol];
        const float sc2 = which ? 1.0f : scale2[dk];
        for (int r = 0; r < 4; ++r) {
          const int grow = grow0 + r;
          float v = acc[m][n][r] + bia;
          if (which == 0) v *= sc2;
          const int bb = grow >> 11, s = grow & (NS - 1);
          outp[(((size_t)(bb * NH + h)) * NS + s) * NDK + dk] = (bf16)v;
        }
      }
    }
  } else {
    for (int m = 0; m < 4; ++m) {
      const int d0 = bm * 128 + wm * 64 + m * 16 + lr4;
      for (int n = 0; n < 4; ++n) {
        const int gcol = bn * 128 + wn * 64 + n * 16 + l15;
        const int bb = gcol >> 11, s = gcol & (NS - 1);
        for (int r = 0; r < 4; ++r) {
          const int d = d0 + r;
          const float v = acc[m][n][r] + bv[d];
          const int h = d >> 6, dk = d & 63;
          Vt[(((size_t)(bb * NH + h)) * NDK + dk) * NS + s] = (bf16)v;
        }
      }
    }
  }
}

// ---------------- post GEMM v2: 64x128 tile, 2-phase double-buffered staging -------------
__global__ __launch_bounds__(256) void post_mm2(
    const bf16* __restrict__ A, const bf16* __restrict__ Bm,
    const float* __restrict__ bias, float* __restrict__ out) {
  __shared__ __align__(16) bf16 la[2][64 * 64];    // 16KB
  __shared__ __align__(16) bf16 lb[2][128 * 64];   // 32KB
  const int t = threadIdx.x, lane = t & 63, wave = t >> 6;
  const int bm = blockIdx.x >> 3, bn = blockIdx.x & 7;
  const int g = lane >> 4, l15 = lane & 15;
  const int sr = wave * 8 + (lane >> 3);
  const int sc = ((lane & 7) ^ (lane >> 3)) * 8;
  const bf16* Abase = A  + (size_t)(bm * 64) * ND;
  const bf16* Bbase = Bm + (size_t)(bn * 128) * ND;

  f32x4 acc[4][2] = {};

  auto stage = [&](int kt, int b) {
    for (int c = 0; c < 2; ++c)
      gload16(Abase + (size_t)(c * 32 + sr) * ND + kt + sc, la[b] + c * 2048 + wave * 512);
    for (int c = 0; c < 4; ++c)
      gload16(Bbase + (size_t)(c * 32 + sr) * ND + kt + sc, lb[b] + c * 2048 + wave * 512);
  };

  stage(0, 0);
  asm volatile("s_waitcnt vmcnt(0)" ::: "memory");
  __builtin_amdgcn_s_barrier();

  for (int it = 0; it < 16; ++it) {
    const int cur = it & 1;
    if (it + 1 < 16) stage((it + 1) * 64, cur ^ 1);

    __builtin_amdgcn_s_setprio(1);
    for (int kk = 0; kk < 2; ++kk) {
      bf16x8 af[4], bfv[2];
      for (int m = 0; m < 4; ++m) {
        const int rr = m * 16 + l15;
        af[m] = *(const bf16x8*)&la[cur][rr * 64 + (((g + 4 * kk) ^ (rr & 7)) << 3)];
      }
      for (int n = 0; n < 2; ++n) {
        const int rr = wave * 32 + n * 16 + l15;
        bfv[n] = *(const bf16x8*)&lb[cur][rr * 64 + (((g + 4 * kk) ^ (rr & 7)) << 3)];
      }
      for (int m = 0; m < 4; ++m)
        for (int n = 0; n < 2; ++n)
          acc[m][n] = mfma16(af[m], bfv[n], acc[m][n]);
    }
    __builtin_amdgcn_s_setprio(0);

    asm volatile("s_waitcnt vmcnt(0)" ::: "memory");
    __builtin_amdgcn_s_barrier();
  }

  for (int m = 0; m < 4; ++m) {
    const int grow0 = bm * 64 + m * 16 + g * 4;
    for (int n = 0; n < 2; ++n) {
      const int gcol = bn * 128 + wave * 32 + n * 16 + l15;
      const float bia = bias[gcol];
      for (int r = 0; r < 4; ++r)
        out[(size_t)(grow0 + r) * ND + gcol] = acc[m][n][r] + bia;
    }
  }
}

// ---------------- flash attention v10: swapped QK^T -> packed b64 P-stores ---------------
__global__ __launch_bounds__(512) void attn10(
    const bf16* __restrict__ Qs, const bf16* __restrict__ Ks,
    const bf16* __restrict__ Vt, const float* __restrict__ mask,
    const int* __restrict__ flag, bf16* __restrict__ Obs) {
  __shared__ __align__(16) bf16 lk[2 * 64 * 64];
  __shared__ __align__(16) bf16 lv[2 * 64 * 64];
  __shared__ __align__(16) bf16 lp[8 * 16 * 64];

  const int t = threadIdx.x, lane = t & 63, wave = t >> 6;
  const int g = lane >> 4, l15 = lane & 15;
  const int bh = blockIdx.y;
  const int qbase = blockIdx.x * 128 + wave * 16;
  const bool use_mask = (*flag) != 0;

  const bf16* Qh = Qs + (size_t)bh * NS * NDK;
  const bf16* Kh = Ks + (size_t)bh * NS * NDK;
  const bf16* Vh = Vt + (size_t)bh * NDK * NS;

  bf16x8 qf[2];
#pragma unroll
  for (int kk = 0; kk < 2; ++kk)
    qf[kk] = *(const bf16x8*)&Qh[(size_t)(qbase + l15) * NDK + kk * 32 + g * 8];

  f32x4 o_acc[4] = {};
  float lsum = 0.0f;   // partial row-sum for q = l15 (this lane's k-subset)

  unsigned kfo[2][4];
#pragma unroll
  for (int kk = 0; kk < 2; ++kk)
#pragma unroll
    for (int n = 0; n < 4; ++n)
      kfo[kk][n] = (unsigned)((n * 16 + l15) * 64 + (((g + 4 * kk) ^ (l15 & 7)) << 3));
  unsigned pw4[4];   // packed P store: q = l15, k = n*16 + g*4 .. +3 (XOR keeps 4-align)
#pragma unroll
  for (int n = 0; n < 4; ++n)
    pw4[n] = (unsigned)(wave * 1024 + l15 * 64 + ((n * 16 + g * 4) ^ ((l15 & 7) << 3)));
  unsigned pro[2];
#pragma unroll
  for (int kk = 0; kk < 2; ++kk)
    pro[kk] = (unsigned)(wave * 1024 + l15 * 64 + ((kk * 32 + g * 8) ^ ((l15 & 7) << 3)));

  const int srow = wave * 8 + (lane >> 3);
  const int sc = ((lane & 7) ^ (lane >> 3)) * 8;

  auto stage = [&](int kv, int b) {
    gload16(Kh + (size_t)(kv + srow) * NDK + sc, lk + b * 4096 + wave * 512);
    gload16(Vh + (size_t)srow * NS + kv + sc, lv + b * 4096 + wave * 512);
  };

  auto body = [&](int kv, int cur) {
    if (kv + 64 < NS) stage(kv + 64, cur ^ 1);

    // S^T = K Q^T (swapped operands): sacc[n][r] is (q=l15, k=kv + n*16 + g*4 + r)
    f32x4 sacc[4] = {};
    __builtin_amdgcn_s_setprio(1);
#pragma unroll
    for (int kk = 0; kk < 2; ++kk)
#pragma unroll
      for (int n = 0; n < 4; ++n)
        sacc[n] = mfma16(*(const bf16x8*)&lk[cur * 4096 + kfo[kk][n]], qf[kk], sacc[n]);
    __builtin_amdgcn_s_setprio(0);

    if (use_mask) {
#pragma unroll
      for (int n = 0; n < 4; ++n)
#pragma unroll
        for (int r = 0; r < 4; ++r)
          sacc[n][r] += LOG2E * mask[(size_t)(qbase + l15) * NS + kv + n * 16 + g * 4 + r];
    }

    // exp; scalar row-sum partial; packed b64 P store (4 consecutive k per lane)
#pragma unroll
    for (int n = 0; n < 4; ++n) {
      bf16x4 pk;
#pragma unroll
      for (int r = 0; r < 4; ++r) {
        const float e = exp2_fast(sacc[n][r]);
        lsum += e;
        pk[r] = (bf16)e;
      }
      *(bf16x4*)&lp[pw4[n]] = pk;
    }

    // O += P @ V (pf: A[row=q=l15][k], unchanged layout)
#pragma unroll
    for (int kk = 0; kk < 2; ++kk) {
      const bf16x8 pf = *(const bf16x8*)&lp[pro[kk]];
      __builtin_amdgcn_s_setprio(1);
#pragma unroll
      for (int n = 0; n < 4; ++n)
        o_acc[n] = mfma16(pf, *(const bf16x8*)&lv[cur * 4096 + kfo[kk][n]], o_acc[n]);
      __builtin_amdgcn_s_setprio(0);
    }

    asm volatile("s_waitcnt vmcnt(0)" ::: "memory");
    __builtin_amdgcn_s_barrier();
  };

  stage(0, 0);
  asm volatile("s_waitcnt vmcnt(0)" ::: "memory");
  __builtin_amdgcn_s_barrier();

  for (int kv = 0; kv < NS; kv += 128) {
    body(kv, 0);
    body(kv + 64, 1);
  }

  // reduce lsum across the 4 g-copies of each q-row (lanes l15, +16, +32, +48)
  float rs = lsum;
  rs += __shfl_xor(rs, 16, 64);
  rs += __shfl_xor(rs, 32, 64);
  const int bidx = bh >> 4, h = bh & 15;
#pragma unroll
  for (int r = 0; r < 4; ++r) {
    const float rsr = __shfl(rs, g * 4 + r, 64);   // lane g*4+r holds l15 = g*4+r
    const float rinv = 1.0f / rsr;
    const int qrow = qbase + g * 4 + r;
#pragma unroll
    for (int n = 0; n < 4; ++n)
      Obs[((size_t)(bidx * NS + qrow)) * ND + h * 64 + n * 16 + l15] = (bf16)(o_acc[n][r] * rinv);
  }
}

extern "C" void kernel_launch(void* const* d_in, const int* in_sizes, int n_in,
                              void* d_out, int out_size, void* d_ws, size_t ws_size,
                              hipStream_t stream) {
  (void)in_sizes; (void)n_in; (void)out_size;
  const float* query = (const float*)d_in[0];
  const float* key   = (const float*)d_in[1];
  const float* value = (const float*)d_in[2];
  const float* mask  = (const float*)d_in[3];
  const float* Wq    = (const float*)d_in[4];
  const float* bq    = (const float*)d_in[5];
  const float* Wk    = (const float*)d_in[6];
  const float* bk    = (const float*)d_in[7];
  const float* Wv    = (const float*)d_in[8];
  const float* bv    = (const float*)d_in[9];
  const float* Wpost = (const float*)d_in[10];
  const float* bpost = (const float*)d_in[11];
  const float* pds   = (const float*)d_in[12];

  char* ws = (char*)d_ws;
  const size_t MB = 1u << 20;
  bf16* Wqb = (bf16*)(ws + 24 * MB);
  bf16* Wkb = (bf16*)(ws + 26 * MB);
  bf16* Wvb = (bf16*)(ws + 28 * MB);
  bf16* Wpb = (bf16*)(ws + 30 * MB);
  float* scale2 = (float*)(ws + 32 * MB);
  int* flag     = (int*)(ws + 32 * MB + 256);

  const bool fused = ws_size >= (size_t)50 * MB;
  bf16 *Qsp, *Ksp, *Vtp, *Obsp;
  if (fused) {
    Qsp = (bf16*)d_out;                       // 8 MB scratch in d_out
    Ksp = (bf16*)((char*)d_out + 8 * MB);     // 8 MB scratch in d_out
    Vtp = (bf16*)(ws + 33 * MB);
    Obsp = (bf16*)(ws + 41 * MB);
  } else {
    Qsp = (bf16*)d_out;
    Ksp = (bf16*)(ws + 0 * MB);
    Vtp = (bf16*)(ws + 8 * MB);
    Obsp = (bf16*)(ws + 16 * MB);
  }

  (void)hipMemsetAsync(flag, 0, sizeof(int), stream);

  cvtw_prep<<<dim3(256, 5), 256, 0, stream>>>(Wq, Wk, Wv, Wpost,
                                              Wqb, Wkb, Wvb, Wpb, ND * ND / 8,
                                              pds, scale2, mask, flag, NS * NS / 4);

  if (fused) {
    qkv_mm<<<dim3(256, 3), 256, 0, stream>>>(query, key, value, Wqb, Wkb, Wvb,
                                             bq, bk, bv, scale2, Qsp, Ksp, Vtp, 0);
  } else {
    qkv_mm<<<dim3(256, 1), 256, 0, stream>>>(query, key, value, Wqb, Wkb, Wvb,
                                             bq, bk, bv, scale2, Qsp, Ksp, Vtp, 0);
    qkv_mm<<<dim3(256, 1), 256, 0, stream>>>(query, key, value, Wqb, Wkb, Wvb,
                                             bq, bk, bv, scale2, Qsp, Ksp, Vtp, 1);
    qkv_mm<<<dim3(256, 1), 256, 0, stream>>>(query, key, value, Wqb, Wkb, Wvb,
                                             bq, bk, bv, scale2, Qsp, Ksp, Vtp, 2);
  }

  attn10<<<dim3(16, 32), 512, 0, stream>>>(Qsp, Ksp, Vtp, mask, flag, Obsp);

  post_mm2<<<512, 256, 0, stream>>>(Obsp, Wpb, bpost, (float*)d_out);
}

// Round 15
// 122.088 us; speedup vs baseline: 1.0842x; 1.0842x over previous
//
#include <hip/hip_runtime.h>
#include <math.h>

typedef __bf16 bf16;
typedef __bf16 bf16x4 __attribute__((ext_vector_type(4)));
typedef __bf16 bf16x8 __attribute__((ext_vector_type(8)));
typedef float f32x4 __attribute__((ext_vector_type(4)));

static constexpr int NB = 2, NS = 2048, ND = 1024, NH = 16, NDK = 64;
static constexpr float LOG2E = 1.442695041f;

__device__ __forceinline__ f32x4 mfma16(bf16x8 a, bf16x8 b, f32x4 c) {
  return __builtin_amdgcn_mfma_f32_16x16x32_bf16(a, b, c, 0, 0, 0);
}

__device__ __forceinline__ float exp2_fast(float x) {
  return __builtin_amdgcn_exp2f(x);
}

// async global->LDS, 16B per lane; dest = wave-uniform base + lane*16
__device__ __forceinline__ void gload16(const void* g, void* l) {
  __builtin_amdgcn_global_load_lds(
      (const __attribute__((address_space(1))) void*)g,
      (__attribute__((address_space(3))) void*)l, 16, 0, 0);
}

// ---------------- fp32 -> bf16 bulk convert (7 tensors) + prep (y==7) ----------------
__global__ __launch_bounds__(256) void cvt_bf16(
    const float* __restrict__ s0, const float* __restrict__ s1, const float* __restrict__ s2,
    const float* __restrict__ s3, const float* __restrict__ s4, const float* __restrict__ s5,
    const float* __restrict__ s6,
    bf16* __restrict__ d0, bf16* __restrict__ d1, bf16* __restrict__ d2,
    bf16* __restrict__ d3, bf16* __restrict__ d4, bf16* __restrict__ d5,
    bf16* __restrict__ d6, int n8x, int n8w,
    const float* __restrict__ pds, float* __restrict__ scale,
    const float* __restrict__ mask, int* __restrict__ flag, int n4) {
  const int y = blockIdx.y;
  if (y == 7) {
    if (blockIdx.x == 0 && threadIdx.x < NDK) {
      float x = pds[threadIdx.x];
      float sp = fmaxf(x, 0.0f) + log1pf(expf(-fabsf(x)));
      scale[threadIdx.x] = (LOG2E * LOG2E / 8.0f) * sp;
    }
    int idx = blockIdx.x * blockDim.x + threadIdx.x;
    int stride = 256 * blockDim.x;
    unsigned acc = 0;
    for (int i = idx; i < n4; i += stride) {
      float4 v = ((const float4*)mask)[i];
      acc |= (__float_as_uint(v.x) << 1) | (__float_as_uint(v.y) << 1)
           | (__float_as_uint(v.z) << 1) | (__float_as_uint(v.w) << 1);
    }
    if (acc != 0) atomicOr(flag, 1);
    return;
  }
  const float* s = y == 0 ? s0 : y == 1 ? s1 : y == 2 ? s2 : y == 3 ? s3
                 : y == 4 ? s4 : y == 5 ? s5 : s6;
  bf16* d = y == 0 ? d0 : y == 1 ? d1 : y == 2 ? d2 : y == 3 ? d3
          : y == 4 ? d4 : y == 5 ? d5 : d6;
  const int n8 = y < 3 ? n8x : n8w;
  for (int i = blockIdx.x * 256 + threadIdx.x; i < n8; i += gridDim.x * 256) {
    const float4* f = (const float4*)s + 2 * (size_t)i;
    float4 a = f[0], b = f[1];
    bf16x8 o;
    o[0] = (bf16)a.x; o[1] = (bf16)a.y; o[2] = (bf16)a.z; o[3] = (bf16)a.w;
    o[4] = (bf16)b.x; o[5] = (bf16)b.y; o[6] = (bf16)b.z; o[7] = (bf16)b.w;
    *((bf16x8*)d + i) = o;
  }
}

// ---------------- fused QKV GEMM: 128x128 tile, BK=64, gload_lds + XOR swizzle -----------
__global__ __launch_bounds__(256) void qkv_mm(
    const bf16* __restrict__ Xq, const bf16* __restrict__ Xk, const bf16* __restrict__ Xv,
    const bf16* __restrict__ Wqb, const bf16* __restrict__ Wkb, const bf16* __restrict__ Wvb,
    const float* __restrict__ bq, const float* __restrict__ bk, const float* __restrict__ bv,
    const float* __restrict__ scale2,
    bf16* __restrict__ Qs, bf16* __restrict__ Ks, bf16* __restrict__ Vt, int mode0) {
  __shared__ __align__(16) bf16 la[128 * 64];
  __shared__ __align__(16) bf16 lb[128 * 64];
  const int which = mode0 + blockIdx.y;
  const bf16* A  = which == 0 ? Xq  : which == 1 ? Xk  : Wvb;
  const bf16* Bm = which == 0 ? Wqb : which == 1 ? Wkb : Xv;
  const int t = threadIdx.x, lane = t & 63, wave = t >> 6;
  const int wm = wave >> 1, wn = wave & 1;
  int bm, bn;
  if (which == 2) { bm = blockIdx.x & 7; bn = blockIdx.x >> 3; }
  else            { bm = blockIdx.x >> 3; bn = blockIdx.x & 7; }
  const int g = lane >> 4, l15 = lane & 15;
  const int sr = wave * 8 + (lane >> 3);
  const int sc = ((lane & 7) ^ (lane >> 3)) * 8;   // swizzled source col (elements)
  const bf16* Abase = A  + (size_t)(bm * 128) * ND;
  const bf16* Bbase = Bm + (size_t)(bn * 128) * ND;

  f32x4 acc[4][4] = {};

  for (int kt = 0; kt < ND; kt += 64) {
    for (int c = 0; c < 4; ++c) {
      gload16(Abase + (size_t)(c * 32 + sr) * ND + kt + sc, la + c * 2048 + wave * 512);
      gload16(Bbase + (size_t)(c * 32 + sr) * ND + kt + sc, lb + c * 2048 + wave * 512);
    }
    __syncthreads();
    __builtin_amdgcn_s_setprio(1);
    for (int kk = 0; kk < 2; ++kk) {
      bf16x8 af[4], bfv[4];
      for (int m = 0; m < 4; ++m) {
        const int rr = wm * 64 + m * 16 + l15;
        af[m] = *(const bf16x8*)&la[rr * 64 + (((g + 4 * kk) ^ (rr & 7)) << 3)];
      }
      for (int n = 0; n < 4; ++n) {
        const int rr = wn * 64 + n * 16 + l15;
        bfv[n] = *(const bf16x8*)&lb[rr * 64 + (((g + 4 * kk) ^ (rr & 7)) << 3)];
      }
      for (int m = 0; m < 4; ++m)
        for (int n = 0; n < 4; ++n)
          acc[m][n] = mfma16(af[m], bfv[n], acc[m][n]);
    }
    __builtin_amdgcn_s_setprio(0);
    __syncthreads();
  }

  const int lr4 = g * 4;
  if (which != 2) {
    const float* bias = which ? bk : bq;
    bf16* outp = which ? Ks : Qs;
    for (int m = 0; m < 4; ++m) {
      const int grow0 = bm * 128 + wm * 64 + m * 16 + lr4;
      for (int n = 0; n < 4; ++n) {
        const int gcol = bn * 128 + wn * 64 + n * 16 + l15;
        const int h = gcol >> 6, dk = gcol & 63;
        const float bia = bias[gcol];
        const float sc2 = which ? 1.0f : scale2[dk];
        for (int r = 0; r < 4; ++r) {
          const int grow = grow0 + r;
          float v = acc[m][n][r] + bia;
          if (which == 0) v *= sc2;
          const int bb = grow >> 11, s = grow & (NS - 1);
          outp[(((size_t)(bb * NH + h)) * NS + s) * NDK + dk] = (bf16)v;
        }
      }
    }
  } else {
    for (int m = 0; m < 4; ++m) {
      const int d0 = bm * 128 + wm * 64 + m * 16 + lr4;
      for (int n = 0; n < 4; ++n) {
        const int gcol = bn * 128 + wn * 64 + n * 16 + l15;
        const int bb = gcol >> 11, s = gcol & (NS - 1);
        for (int r = 0; r < 4; ++r) {
          const int d = d0 + r;
          const float v = acc[m][n][r] + bv[d];
          const int h = d >> 6, dk = d & 63;
          Vt[(((size_t)(bb * NH + h)) * NDK + dk) * NS + s] = (bf16)v;
        }
      }
    }
  }
}

// ---------------- post GEMM v2: 64x128 tile, 2-phase double-buffered staging -------------
__global__ __launch_bounds__(256) void post_mm2(
    const bf16* __restrict__ A, const bf16* __restrict__ Bm,
    const float* __restrict__ bias, float* __restrict__ out) {
  __shared__ __align__(16) bf16 la[2][64 * 64];    // 16KB
  __shared__ __align__(16) bf16 lb[2][128 * 64];   // 32KB
  const int t = threadIdx.x, lane = t & 63, wave = t >> 6;
  const int bm = blockIdx.x >> 3, bn = blockIdx.x & 7;
  const int g = lane >> 4, l15 = lane & 15;
  const int sr = wave * 8 + (lane >> 3);
  const int sc = ((lane & 7) ^ (lane >> 3)) * 8;
  const bf16* Abase = A  + (size_t)(bm * 64) * ND;
  const bf16* Bbase = Bm + (size_t)(bn * 128) * ND;

  f32x4 acc[4][2] = {};

  auto stage = [&](int kt, int b) {
    for (int c = 0; c < 2; ++c)
      gload16(Abase + (size_t)(c * 32 + sr) * ND + kt + sc, la[b] + c * 2048 + wave * 512);
    for (int c = 0; c < 4; ++c)
      gload16(Bbase + (size_t)(c * 32 + sr) * ND + kt + sc, lb[b] + c * 2048 + wave * 512);
  };

  stage(0, 0);
  asm volatile("s_waitcnt vmcnt(0)" ::: "memory");
  __builtin_amdgcn_s_barrier();

  for (int it = 0; it < 16; ++it) {
    const int cur = it & 1;
    if (it + 1 < 16) stage((it + 1) * 64, cur ^ 1);

    __builtin_amdgcn_s_setprio(1);
    for (int kk = 0; kk < 2; ++kk) {
      bf16x8 af[4], bfv[2];
      for (int m = 0; m < 4; ++m) {
        const int rr = m * 16 + l15;
        af[m] = *(const bf16x8*)&la[cur][rr * 64 + (((g + 4 * kk) ^ (rr & 7)) << 3)];
      }
      for (int n = 0; n < 2; ++n) {
        const int rr = wave * 32 + n * 16 + l15;
        bfv[n] = *(const bf16x8*)&lb[cur][rr * 64 + (((g + 4 * kk) ^ (rr & 7)) << 3)];
      }
      for (int m = 0; m < 4; ++m)
        for (int n = 0; n < 2; ++n)
          acc[m][n] = mfma16(af[m], bfv[n], acc[m][n]);
    }
    __builtin_amdgcn_s_setprio(0);

    asm volatile("s_waitcnt vmcnt(0)" ::: "memory");
    __builtin_amdgcn_s_barrier();
  }

  for (int m = 0; m < 4; ++m) {
    const int grow0 = bm * 64 + m * 16 + g * 4;
    for (int n = 0; n < 2; ++n) {
      const int gcol = bn * 128 + wave * 32 + n * 16 + l15;
      const float bia = bias[gcol];
      for (int r = 0; r < 4; ++r)
        out[(size_t)(grow0 + r) * ND + gcol] = acc[m][n][r] + bia;
    }
  }
}

// ---------------- flash attention v10b: swapped QK^T, packed b64 P-stores, XCD-grouped ---
// Grid remap: L = x + 16*y; bh = (L&7)*4 + ((L>>3)&3); qtile = L>>5. All 16 q-tile blocks
// sharing one head's K/V satisfy L%8 == const -> same XCD (round-robin dispatch) -> K/V
// panel fetched once per XCD instead of 8x. Bijective; correctness mapping-independent.
__global__ __launch_bounds__(512) void attn10(
    const bf16* __restrict__ Qs, const bf16* __restrict__ Ks,
    const bf16* __restrict__ Vt, const float* __restrict__ mask,
    const int* __restrict__ flag, bf16* __restrict__ Obs) {
  __shared__ __align__(16) bf16 lk[2 * 64 * 64];
  __shared__ __align__(16) bf16 lv[2 * 64 * 64];
  __shared__ __align__(16) bf16 lp[8 * 16 * 64];

  const int t = threadIdx.x, lane = t & 63, wave = t >> 6;
  const int g = lane >> 4, l15 = lane & 15;
  const int L = blockIdx.x + 16 * blockIdx.y;
  const int bh = (L & 7) * 4 + ((L >> 3) & 3);
  const int qbase = (L >> 5) * 128 + wave * 16;
  const bool use_mask = (*flag) != 0;

  const bf16* Qh = Qs + (size_t)bh * NS * NDK;
  const bf16* Kh = Ks + (size_t)bh * NS * NDK;
  const bf16* Vh = Vt + (size_t)bh * NDK * NS;

  bf16x8 qf[2];
#pragma unroll
  for (int kk = 0; kk < 2; ++kk)
    qf[kk] = *(const bf16x8*)&Qh[(size_t)(qbase + l15) * NDK + kk * 32 + g * 8];

  f32x4 o_acc[4] = {};
  float lsum = 0.0f;   // partial row-sum for q = l15 (this lane's k-subset)

  unsigned kfo[2][4];
#pragma unroll
  for (int kk = 0; kk < 2; ++kk)
#pragma unroll
    for (int n = 0; n < 4; ++n)
      kfo[kk][n] = (unsigned)((n * 16 + l15) * 64 + (((g + 4 * kk) ^ (l15 & 7)) << 3));
  unsigned pw4[4];   // packed P store: q = l15, k = n*16 + g*4 .. +3 (XOR keeps 4-align)
#pragma unroll
  for (int n = 0; n < 4; ++n)
    pw4[n] = (unsigned)(wave * 1024 + l15 * 64 + ((n * 16 + g * 4) ^ ((l15 & 7) << 3)));
  unsigned pro[2];
#pragma unroll
  for (int kk = 0; kk < 2; ++kk)
    pro[kk] = (unsigned)(wave * 1024 + l15 * 64 + ((kk * 32 + g * 8) ^ ((l15 & 7) << 3)));

  const int srow = wave * 8 + (lane >> 3);
  const int sc = ((lane & 7) ^ (lane >> 3)) * 8;

  auto stage = [&](int kv, int b) {
    gload16(Kh + (size_t)(kv + srow) * NDK + sc, lk + b * 4096 + wave * 512);
    gload16(Vh + (size_t)srow * NS + kv + sc, lv + b * 4096 + wave * 512);
  };

  auto body = [&](int kv, int cur) {
    if (kv + 64 < NS) stage(kv + 64, cur ^ 1);

    // S^T = K Q^T (swapped operands): sacc[n][r] is (q=l15, k=kv + n*16 + g*4 + r)
    f32x4 sacc[4] = {};
    __builtin_amdgcn_s_setprio(1);
#pragma unroll
    for (int kk = 0; kk < 2; ++kk)
#pragma unroll
      for (int n = 0; n < 4; ++n)
        sacc[n] = mfma16(*(const bf16x8*)&lk[cur * 4096 + kfo[kk][n]], qf[kk], sacc[n]);
    __builtin_amdgcn_s_setprio(0);

    if (use_mask) {
#pragma unroll
      for (int n = 0; n < 4; ++n)
#pragma unroll
        for (int r = 0; r < 4; ++r)
          sacc[n][r] += LOG2E * mask[(size_t)(qbase + l15) * NS + kv + n * 16 + g * 4 + r];
    }

    // exp; scalar row-sum partial; packed b64 P store (4 consecutive k per lane)
#pragma unroll
    for (int n = 0; n < 4; ++n) {
      bf16x4 pk;
#pragma unroll
      for (int r = 0; r < 4; ++r) {
        const float e = exp2_fast(sacc[n][r]);
        lsum += e;
        pk[r] = (bf16)e;
      }
      *(bf16x4*)&lp[pw4[n]] = pk;
    }

    // O += P @ V (pf: A[row=q=l15][k], unchanged layout)
#pragma unroll
    for (int kk = 0; kk < 2; ++kk) {
      const bf16x8 pf = *(const bf16x8*)&lp[pro[kk]];
      __builtin_amdgcn_s_setprio(1);
#pragma unroll
      for (int n = 0; n < 4; ++n)
        o_acc[n] = mfma16(pf, *(const bf16x8*)&lv[cur * 4096 + kfo[kk][n]], o_acc[n]);
      __builtin_amdgcn_s_setprio(0);
    }

    asm volatile("s_waitcnt vmcnt(0)" ::: "memory");
    __builtin_amdgcn_s_barrier();
  };

  stage(0, 0);
  asm volatile("s_waitcnt vmcnt(0)" ::: "memory");
  __builtin_amdgcn_s_barrier();

  for (int kv = 0; kv < NS; kv += 128) {
    body(kv, 0);
    body(kv + 64, 1);
  }

  // reduce lsum across the 4 g-copies of each q-row (lanes l15, +16, +32, +48)
  float rs = lsum;
  rs += __shfl_xor(rs, 16, 64);
  rs += __shfl_xor(rs, 32, 64);
  const int bidx = bh >> 4, h = bh & 15;
#pragma unroll
  for (int r = 0; r < 4; ++r) {
    const float rsr = __shfl(rs, g * 4 + r, 64);   // lane g*4+r holds l15 = g*4+r
    const float rinv = 1.0f / rsr;
    const int qrow = qbase + g * 4 + r;
#pragma unroll
    for (int n = 0; n < 4; ++n)
      Obs[((size_t)(bidx * NS + qrow)) * ND + h * 64 + n * 16 + l15] = (bf16)(o_acc[n][r] * rinv);
  }
}

extern "C" void kernel_launch(void* const* d_in, const int* in_sizes, int n_in,
                              void* d_out, int out_size, void* d_ws, size_t ws_size,
                              hipStream_t stream) {
  (void)in_sizes; (void)n_in; (void)out_size;
  const float* query = (const float*)d_in[0];
  const float* key   = (const float*)d_in[1];
  const float* value = (const float*)d_in[2];
  const float* mask  = (const float*)d_in[3];
  const float* Wq    = (const float*)d_in[4];
  const float* bq    = (const float*)d_in[5];
  const float* Wk    = (const float*)d_in[6];
  const float* bk    = (const float*)d_in[7];
  const float* Wv    = (const float*)d_in[8];
  const float* bv    = (const float*)d_in[9];
  const float* Wpost = (const float*)d_in[10];
  const float* bpost = (const float*)d_in[11];
  const float* pds   = (const float*)d_in[12];

  char* ws = (char*)d_ws;
  const size_t MB = 1u << 20;
  bf16* Xq  = (bf16*)(ws + 0 * MB);
  bf16* Xk  = (bf16*)(ws + 8 * MB);
  bf16* Xv  = (bf16*)(ws + 16 * MB);
  bf16* Wqb = (bf16*)(ws + 24 * MB);
  bf16* Wkb = (bf16*)(ws + 26 * MB);
  bf16* Wvb = (bf16*)(ws + 28 * MB);
  bf16* Wpb = (bf16*)(ws + 30 * MB);
  float* scale2 = (float*)(ws + 32 * MB);
  int* flag     = (int*)(ws + 32 * MB + 256);

  const bool fused = ws_size >= (size_t)50 * MB;
  bf16 *Qsp, *Ksp, *Vtp, *Obsp;
  if (fused) {
    Qsp = (bf16*)d_out;                       // 8 MB scratch in d_out
    Ksp = (bf16*)((char*)d_out + 8 * MB);     // 8 MB scratch in d_out
    Vtp = (bf16*)(ws + 33 * MB);
    Obsp = (bf16*)(ws + 41 * MB);
  } else {
    Qsp = (bf16*)d_out;
    Ksp = Xq;   // Xq dead after Q GEMM
    Vtp = Xk;   // Xk dead after K GEMM
    Obsp = Xv;  // Xv dead after V GEMM
  }

  (void)hipMemsetAsync(flag, 0, sizeof(int), stream);

  cvt_bf16<<<dim3(256, 8), 256, 0, stream>>>(query, key, value, Wq, Wk, Wv, Wpost,
                                             Xq, Xk, Xv, Wqb, Wkb, Wvb, Wpb,
                                             NB * NS * ND / 8, ND * ND / 8,
                                             pds, scale2, mask, flag, NS * NS / 4);

  if (fused) {
    qkv_mm<<<dim3(256, 3), 256, 0, stream>>>(Xq, Xk, Xv, Wqb, Wkb, Wvb,
                                             bq, bk, bv, scale2, Qsp, Ksp, Vtp, 0);
  } else {
    qkv_mm<<<dim3(256, 1), 256, 0, stream>>>(Xq, Xk, Xv, Wqb, Wkb, Wvb,
                                             bq, bk, bv, scale2, Qsp, Ksp, Vtp, 0);
    qkv_mm<<<dim3(256, 1), 256, 0, stream>>>(Xq, Xk, Xv, Wqb, Wkb, Wvb,
                                             bq, bk, bv, scale2, Qsp, Ksp, Vtp, 1);
    qkv_mm<<<dim3(256, 1), 256, 0, stream>>>(Xq, Xk, Xv, Wqb, Wkb, Wvb,
                                             bq, bk, bv, scale2, Qsp, Ksp, Vtp, 2);
  }

  attn10<<<dim3(16, 32), 512, 0, stream>>>(Qsp, Ksp, Vtp, mask, flag, Obsp);

  post_mm2<<<512, 256, 0, stream>>>(Obsp, Wpb, bpost, (float*)d_out);
}

// Round 16
// 120.026 us; speedup vs baseline: 1.1029x; 1.0172x over previous
//
#include <hip/hip_runtime.h>
#include <math.h>

typedef __bf16 bf16;
typedef __bf16 bf16x4 __attribute__((ext_vector_type(4)));
typedef __bf16 bf16x8 __attribute__((ext_vector_type(8)));
typedef float f32x4 __attribute__((ext_vector_type(4)));

static constexpr int NB = 2, NS = 2048, ND = 1024, NH = 16, NDK = 64;
static constexpr float LOG2E = 1.442695041f;

__device__ __forceinline__ f32x4 mfma16(bf16x8 a, bf16x8 b, f32x4 c) {
  return __builtin_amdgcn_mfma_f32_16x16x32_bf16(a, b, c, 0, 0, 0);
}

__device__ __forceinline__ float exp2_fast(float x) {
  return __builtin_amdgcn_exp2f(x);
}

// async global->LDS, 16B per lane; dest = wave-uniform base + lane*16
__device__ __forceinline__ void gload16(const void* g, void* l) {
  __builtin_amdgcn_global_load_lds(
      (const __attribute__((address_space(1))) void*)g,
      (__attribute__((address_space(3))) void*)l, 16, 0, 0);
}

// ---------------- fp32 -> bf16 bulk convert (7 tensors) + prep (y==7) ----------------
__global__ __launch_bounds__(256) void cvt_bf16(
    const float* __restrict__ s0, const float* __restrict__ s1, const float* __restrict__ s2,
    const float* __restrict__ s3, const float* __restrict__ s4, const float* __restrict__ s5,
    const float* __restrict__ s6,
    bf16* __restrict__ d0, bf16* __restrict__ d1, bf16* __restrict__ d2,
    bf16* __restrict__ d3, bf16* __restrict__ d4, bf16* __restrict__ d5,
    bf16* __restrict__ d6, int n8x, int n8w,
    const float* __restrict__ pds, float* __restrict__ scale,
    const float* __restrict__ mask, int* __restrict__ flag, int n4) {
  const int y = blockIdx.y;
  if (y == 7) {
    if (blockIdx.x == 0 && threadIdx.x < NDK) {
      float x = pds[threadIdx.x];
      float sp = fmaxf(x, 0.0f) + log1pf(expf(-fabsf(x)));
      scale[threadIdx.x] = (LOG2E * LOG2E / 8.0f) * sp;
    }
    int idx = blockIdx.x * blockDim.x + threadIdx.x;
    int stride = 256 * blockDim.x;
    unsigned acc = 0;
    for (int i = idx; i < n4; i += stride) {
      float4 v = ((const float4*)mask)[i];
      acc |= (__float_as_uint(v.x) << 1) | (__float_as_uint(v.y) << 1)
           | (__float_as_uint(v.z) << 1) | (__float_as_uint(v.w) << 1);
    }
    if (acc != 0) atomicOr(flag, 1);
    return;
  }
  const float* s = y == 0 ? s0 : y == 1 ? s1 : y == 2 ? s2 : y == 3 ? s3
                 : y == 4 ? s4 : y == 5 ? s5 : s6;
  bf16* d = y == 0 ? d0 : y == 1 ? d1 : y == 2 ? d2 : y == 3 ? d3
          : y == 4 ? d4 : y == 5 ? d5 : d6;
  const int n8 = y < 3 ? n8x : n8w;
  for (int i = blockIdx.x * 256 + threadIdx.x; i < n8; i += gridDim.x * 256) {
    const float4* f = (const float4*)s + 2 * (size_t)i;
    float4 a = f[0], b = f[1];
    bf16x8 o;
    o[0] = (bf16)a.x; o[1] = (bf16)a.y; o[2] = (bf16)a.z; o[3] = (bf16)a.w;
    o[4] = (bf16)b.x; o[5] = (bf16)b.y; o[6] = (bf16)b.z; o[7] = (bf16)b.w;
    *((bf16x8*)d + i) = o;
  }
}

// ---------------- fused QKV GEMM: 128x128 tile, BK=64, XCD-grouped token panels ----------
// Token(X)-panel index in blockIdx.x low 5 bits: the 8 blocks sharing one X panel are
// x = p, p+32, ... (all == p mod 8) -> same XCD -> X panel fetched once per XCD. Weight
// panels (2MB/slice) get refetched instead -- 4x less traffic than the reverse mapping.
__global__ __launch_bounds__(256) void qkv_mm(
    const bf16* __restrict__ Xq, const bf16* __restrict__ Xk, const bf16* __restrict__ Xv,
    const bf16* __restrict__ Wqb, const bf16* __restrict__ Wkb, const bf16* __restrict__ Wvb,
    const float* __restrict__ bq, const float* __restrict__ bk, const float* __restrict__ bv,
    const float* __restrict__ scale2,
    bf16* __restrict__ Qs, bf16* __restrict__ Ks, bf16* __restrict__ Vt, int mode0) {
  __shared__ __align__(16) bf16 la[128 * 64];
  __shared__ __align__(16) bf16 lb[128 * 64];
  const int which = mode0 + blockIdx.y;
  const bf16* A  = which == 0 ? Xq  : which == 1 ? Xk  : Wvb;
  const bf16* Bm = which == 0 ? Wqb : which == 1 ? Wkb : Xv;
  const int t = threadIdx.x, lane = t & 63, wave = t >> 6;
  const int wm = wave >> 1, wn = wave & 1;
  // token-panel index in low 5 bits (32 panels), weight-panel in high 3 bits
  int bm, bn;
  if (which == 2) { bn = blockIdx.x & 31; bm = blockIdx.x >> 5; }   // bn = Xv token panel
  else            { bm = blockIdx.x & 31; bn = blockIdx.x >> 5; }   // bm = X token panel
  const int g = lane >> 4, l15 = lane & 15;
  const int sr = wave * 8 + (lane >> 3);
  const int sc = ((lane & 7) ^ (lane >> 3)) * 8;   // swizzled source col (elements)
  const bf16* Abase = A  + (size_t)(bm * 128) * ND;
  const bf16* Bbase = Bm + (size_t)(bn * 128) * ND;

  f32x4 acc[4][4] = {};

  for (int kt = 0; kt < ND; kt += 64) {
    for (int c = 0; c < 4; ++c) {
      gload16(Abase + (size_t)(c * 32 + sr) * ND + kt + sc, la + c * 2048 + wave * 512);
      gload16(Bbase + (size_t)(c * 32 + sr) * ND + kt + sc, lb + c * 2048 + wave * 512);
    }
    __syncthreads();
    __builtin_amdgcn_s_setprio(1);
    for (int kk = 0; kk < 2; ++kk) {
      bf16x8 af[4], bfv[4];
      for (int m = 0; m < 4; ++m) {
        const int rr = wm * 64 + m * 16 + l15;
        af[m] = *(const bf16x8*)&la[rr * 64 + (((g + 4 * kk) ^ (rr & 7)) << 3)];
      }
      for (int n = 0; n < 4; ++n) {
        const int rr = wn * 64 + n * 16 + l15;
        bfv[n] = *(const bf16x8*)&lb[rr * 64 + (((g + 4 * kk) ^ (rr & 7)) << 3)];
      }
      for (int m = 0; m < 4; ++m)
        for (int n = 0; n < 4; ++n)
          acc[m][n] = mfma16(af[m], bfv[n], acc[m][n]);
    }
    __builtin_amdgcn_s_setprio(0);
    __syncthreads();
  }

  const int lr4 = g * 4;
  if (which != 2) {
    const float* bias = which ? bk : bq;
    bf16* outp = which ? Ks : Qs;
    for (int m = 0; m < 4; ++m) {
      const int grow0 = bm * 128 + wm * 64 + m * 16 + lr4;
      for (int n = 0; n < 4; ++n) {
        const int gcol = bn * 128 + wn * 64 + n * 16 + l15;
        const int h = gcol >> 6, dk = gcol & 63;
        const float bia = bias[gcol];
        const float sc2 = which ? 1.0f : scale2[dk];
        for (int r = 0; r < 4; ++r) {
          const int grow = grow0 + r;
          float v = acc[m][n][r] + bia;
          if (which == 0) v *= sc2;
          const int bb = grow >> 11, s = grow & (NS - 1);
          outp[(((size_t)(bb * NH + h)) * NS + s) * NDK + dk] = (bf16)v;
        }
      }
    }
  } else {
    for (int m = 0; m < 4; ++m) {
      const int d0 = bm * 128 + wm * 64 + m * 16 + lr4;
      for (int n = 0; n < 4; ++n) {
        const int gcol = bn * 128 + wn * 64 + n * 16 + l15;
        const int bb = gcol >> 11, s = gcol & (NS - 1);
        for (int r = 0; r < 4; ++r) {
          const int d = d0 + r;
          const float v = acc[m][n][r] + bv[d];
          const int h = d >> 6, dk = d & 63;
          Vt[(((size_t)(bb * NH + h)) * NDK + dk) * NS + s] = (bf16)v;
        }
      }
    }
  }
}

// ---------------- post GEMM v2: 64x128 tile, dbuf staging, XCD-grouped token panels ------
// Obs token panel (128KB, shared by 8 blocks) in low 6 bits -> same XCD; Wpost panels
// refetched instead (4x less traffic).
__global__ __launch_bounds__(256) void post_mm2(
    const bf16* __restrict__ A, const bf16* __restrict__ Bm,
    const float* __restrict__ bias, float* __restrict__ out) {
  __shared__ __align__(16) bf16 la[2][64 * 64];    // 16KB
  __shared__ __align__(16) bf16 lb[2][128 * 64];   // 32KB
  const int t = threadIdx.x, lane = t & 63, wave = t >> 6;
  const int bm = blockIdx.x & 63, bn = blockIdx.x >> 6;   // bm = Obs token panel
  const int g = lane >> 4, l15 = lane & 15;
  const int sr = wave * 8 + (lane >> 3);
  const int sc = ((lane & 7) ^ (lane >> 3)) * 8;
  const bf16* Abase = A  + (size_t)(bm * 64) * ND;
  const bf16* Bbase = Bm + (size_t)(bn * 128) * ND;

  f32x4 acc[4][2] = {};

  auto stage = [&](int kt, int b) {
    for (int c = 0; c < 2; ++c)
      gload16(Abase + (size_t)(c * 32 + sr) * ND + kt + sc, la[b] + c * 2048 + wave * 512);
    for (int c = 0; c < 4; ++c)
      gload16(Bbase + (size_t)(c * 32 + sr) * ND + kt + sc, lb[b] + c * 2048 + wave * 512);
  };

  stage(0, 0);
  asm volatile("s_waitcnt vmcnt(0)" ::: "memory");
  __builtin_amdgcn_s_barrier();

  for (int it = 0; it < 16; ++it) {
    const int cur = it & 1;
    if (it + 1 < 16) stage((it + 1) * 64, cur ^ 1);

    __builtin_amdgcn_s_setprio(1);
    for (int kk = 0; kk < 2; ++kk) {
      bf16x8 af[4], bfv[2];
      for (int m = 0; m < 4; ++m) {
        const int rr = m * 16 + l15;
        af[m] = *(const bf16x8*)&la[cur][rr * 64 + (((g + 4 * kk) ^ (rr & 7)) << 3)];
      }
      for (int n = 0; n < 2; ++n) {
        const int rr = wave * 32 + n * 16 + l15;
        bfv[n] = *(const bf16x8*)&lb[cur][rr * 64 + (((g + 4 * kk) ^ (rr & 7)) << 3)];
      }
      for (int m = 0; m < 4; ++m)
        for (int n = 0; n < 2; ++n)
          acc[m][n] = mfma16(af[m], bfv[n], acc[m][n]);
    }
    __builtin_amdgcn_s_setprio(0);

    asm volatile("s_waitcnt vmcnt(0)" ::: "memory");
    __builtin_amdgcn_s_barrier();
  }

  for (int m = 0; m < 4; ++m) {
    const int grow0 = bm * 64 + m * 16 + g * 4;
    for (int n = 0; n < 2; ++n) {
      const int gcol = bn * 128 + wave * 32 + n * 16 + l15;
      const float bia = bias[gcol];
      for (int r = 0; r < 4; ++r)
        out[(size_t)(grow0 + r) * ND + gcol] = acc[m][n][r] + bia;
    }
  }
}

// ---------------- flash attention v10b: swapped QK^T, packed b64 P-stores, XCD-grouped ---
__global__ __launch_bounds__(512) void attn10(
    const bf16* __restrict__ Qs, const bf16* __restrict__ Ks,
    const bf16* __restrict__ Vt, const float* __restrict__ mask,
    const int* __restrict__ flag, bf16* __restrict__ Obs) {
  __shared__ __align__(16) bf16 lk[2 * 64 * 64];
  __shared__ __align__(16) bf16 lv[2 * 64 * 64];
  __shared__ __align__(16) bf16 lp[8 * 16 * 64];

  const int t = threadIdx.x, lane = t & 63, wave = t >> 6;
  const int g = lane >> 4, l15 = lane & 15;
  const int L = blockIdx.x + 16 * blockIdx.y;
  const int bh = (L & 7) * 4 + ((L >> 3) & 3);
  const int qbase = (L >> 5) * 128 + wave * 16;
  const bool use_mask = (*flag) != 0;

  const bf16* Qh = Qs + (size_t)bh * NS * NDK;
  const bf16* Kh = Ks + (size_t)bh * NS * NDK;
  const bf16* Vh = Vt + (size_t)bh * NDK * NS;

  bf16x8 qf[2];
#pragma unroll
  for (int kk = 0; kk < 2; ++kk)
    qf[kk] = *(const bf16x8*)&Qh[(size_t)(qbase + l15) * NDK + kk * 32 + g * 8];

  f32x4 o_acc[4] = {};
  float lsum = 0.0f;   // partial row-sum for q = l15 (this lane's k-subset)

  unsigned kfo[2][4];
#pragma unroll
  for (int kk = 0; kk < 2; ++kk)
#pragma unroll
    for (int n = 0; n < 4; ++n)
      kfo[kk][n] = (unsigned)((n * 16 + l15) * 64 + (((g + 4 * kk) ^ (l15 & 7)) << 3));
  unsigned pw4[4];   // packed P store: q = l15, k = n*16 + g*4 .. +3 (XOR keeps 4-align)
#pragma unroll
  for (int n = 0; n < 4; ++n)
    pw4[n] = (unsigned)(wave * 1024 + l15 * 64 + ((n * 16 + g * 4) ^ ((l15 & 7) << 3)));
  unsigned pro[2];
#pragma unroll
  for (int kk = 0; kk < 2; ++kk)
    pro[kk] = (unsigned)(wave * 1024 + l15 * 64 + ((kk * 32 + g * 8) ^ ((l15 & 7) << 3)));

  const int srow = wave * 8 + (lane >> 3);
  const int sc = ((lane & 7) ^ (lane >> 3)) * 8;

  auto stage = [&](int kv, int b) {
    gload16(Kh + (size_t)(kv + srow) * NDK + sc, lk + b * 4096 + wave * 512);
    gload16(Vh + (size_t)srow * NS + kv + sc, lv + b * 4096 + wave * 512);
  };

  auto body = [&](int kv, int cur) {
    if (kv + 64 < NS) stage(kv + 64, cur ^ 1);

    // S^T = K Q^T (swapped operands): sacc[n][r] is (q=l15, k=kv + n*16 + g*4 + r)
    f32x4 sacc[4] = {};
    __builtin_amdgcn_s_setprio(1);
#pragma unroll
    for (int kk = 0; kk < 2; ++kk)
#pragma unroll
      for (int n = 0; n < 4; ++n)
        sacc[n] = mfma16(*(const bf16x8*)&lk[cur * 4096 + kfo[kk][n]], qf[kk], sacc[n]);
    __builtin_amdgcn_s_setprio(0);

    if (use_mask) {
#pragma unroll
      for (int n = 0; n < 4; ++n)
#pragma unroll
        for (int r = 0; r < 4; ++r)
          sacc[n][r] += LOG2E * mask[(size_t)(qbase + l15) * NS + kv + n * 16 + g * 4 + r];
    }

    // exp; scalar row-sum partial; packed b64 P store (4 consecutive k per lane)
#pragma unroll
    for (int n = 0; n < 4; ++n) {
      bf16x4 pk;
#pragma unroll
      for (int r = 0; r < 4; ++r) {
        const float e = exp2_fast(sacc[n][r]);
        lsum += e;
        pk[r] = (bf16)e;
      }
      *(bf16x4*)&lp[pw4[n]] = pk;
    }

    // O += P @ V (pf: A[row=q=l15][k], unchanged layout)
#pragma unroll
    for (int kk = 0; kk < 2; ++kk) {
      const bf16x8 pf = *(const bf16x8*)&lp[pro[kk]];
      __builtin_amdgcn_s_setprio(1);
#pragma unroll
      for (int n = 0; n < 4; ++n)
        o_acc[n] = mfma16(pf, *(const bf16x8*)&lv[cur * 4096 + kfo[kk][n]], o_acc[n]);
      __builtin_amdgcn_s_setprio(0);
    }

    asm volatile("s_waitcnt vmcnt(0)" ::: "memory");
    __builtin_amdgcn_s_barrier();
  };

  stage(0, 0);
  asm volatile("s_waitcnt vmcnt(0)" ::: "memory");
  __builtin_amdgcn_s_barrier();

  for (int kv = 0; kv < NS; kv += 128) {
    body(kv, 0);
    body(kv + 64, 1);
  }

  // reduce lsum across the 4 g-copies of each q-row (lanes l15, +16, +32, +48)
  float rs = lsum;
  rs += __shfl_xor(rs, 16, 64);
  rs += __shfl_xor(rs, 32, 64);
  const int bidx = bh >> 4, h = bh & 15;
#pragma unroll
  for (int r = 0; r < 4; ++r) {
    const float rsr = __shfl(rs, g * 4 + r, 64);   // lane g*4+r holds l15 = g*4+r
    const float rinv = 1.0f / rsr;
    const int qrow = qbase + g * 4 + r;
#pragma unroll
    for (int n = 0; n < 4; ++n)
      Obs[((size_t)(bidx * NS + qrow)) * ND + h * 64 + n * 16 + l15] = (bf16)(o_acc[n][r] * rinv);
  }
}

extern "C" void kernel_launch(void* const* d_in, const int* in_sizes, int n_in,
                              void* d_out, int out_size, void* d_ws, size_t ws_size,
                              hipStream_t stream) {
  (void)in_sizes; (void)n_in; (void)out_size;
  const float* query = (const float*)d_in[0];
  const float* key   = (const float*)d_in[1];
  const float* value = (const float*)d_in[2];
  const float* mask  = (const float*)d_in[3];
  const float* Wq    = (const float*)d_in[4];
  const float* bq    = (const float*)d_in[5];
  const float* Wk    = (const float*)d_in[6];
  const float* bk    = (const float*)d_in[7];
  const float* Wv    = (const float*)d_in[8];
  const float* bv    = (const float*)d_in[9];
  const float* Wpost = (const float*)d_in[10];
  const float* bpost = (const float*)d_in[11];
  const float* pds   = (const float*)d_in[12];

  char* ws = (char*)d_ws;
  const size_t MB = 1u << 20;
  bf16* Xq  = (bf16*)(ws + 0 * MB);
  bf16* Xk  = (bf16*)(ws + 8 * MB);
  bf16* Xv  = (bf16*)(ws + 16 * MB);
  bf16* Wqb = (bf16*)(ws + 24 * MB);
  bf16* Wkb = (bf16*)(ws + 26 * MB);
  bf16* Wvb = (bf16*)(ws + 28 * MB);
  bf16* Wpb = (bf16*)(ws + 30 * MB);
  float* scale2 = (float*)(ws + 32 * MB);
  int* flag     = (int*)(ws + 32 * MB + 256);

  const bool fused = ws_size >= (size_t)50 * MB;
  bf16 *Qsp, *Ksp, *Vtp, *Obsp;
  if (fused) {
    Qsp = (bf16*)d_out;                       // 8 MB scratch in d_out
    Ksp = (bf16*)((char*)d_out + 8 * MB);     // 8 MB scratch in d_out
    Vtp = (bf16*)(ws + 33 * MB);
    Obsp = (bf16*)(ws + 41 * MB);
  } else {
    Qsp = (bf16*)d_out;
    Ksp = Xq;   // Xq dead after Q GEMM
    Vtp = Xk;   // Xk dead after K GEMM
    Obsp = Xv;  // Xv dead after V GEMM
  }

  (void)hipMemsetAsync(flag, 0, sizeof(int), stream);

  cvt_bf16<<<dim3(256, 8), 256, 0, stream>>>(query, key, value, Wq, Wk, Wv, Wpost,
                                             Xq, Xk, Xv, Wqb, Wkb, Wvb, Wpb,
                                             NB * NS * ND / 8, ND * ND / 8,
                                             pds, scale2, mask, flag, NS * NS / 4);

  if (fused) {
    qkv_mm<<<dim3(256, 3), 256, 0, stream>>>(Xq, Xk, Xv, Wqb, Wkb, Wvb,
                                             bq, bk, bv, scale2, Qsp, Ksp, Vtp, 0);
  } else {
    qkv_mm<<<dim3(256, 1), 256, 0, stream>>>(Xq, Xk, Xv, Wqb, Wkb, Wvb,
                                             bq, bk, bv, scale2, Qsp, Ksp, Vtp, 0);
    qkv_mm<<<dim3(256, 1), 256, 0, stream>>>(Xq, Xk, Xv, Wqb, Wkb, Wvb,
                                             bq, bk, bv, scale2, Qsp, Ksp, Vtp, 1);
    qkv_mm<<<dim3(256, 1), 256, 0, stream>>>(Xq, Xk, Xv, Wqb, Wkb, Wvb,
                                             bq, bk, bv, scale2, Qsp, Ksp, Vtp, 2);
  }

  attn10<<<dim3(16, 32), 512, 0, stream>>>(Qsp, Ksp, Vtp, mask, flag, Obsp);

  post_mm2<<<512, 256, 0, stream>>>(Obsp, Wpb, bpost, (float*)d_out);
}